// Round 19
// baseline (815.348 us; speedup 1.0000x reference)
//
#include <hip/hip_runtime.h>

#define THREADS 256

typedef __bf16    bf16x8 __attribute__((ext_vector_type(8)));
typedef _Float16  f16x8  __attribute__((ext_vector_type(8)));
typedef float     f32x4  __attribute__((ext_vector_type(4)));
typedef float     f32x16 __attribute__((ext_vector_type(16)));

// ================= CSR build: histogram -> scan -> scatter =================

__global__ __launch_bounds__(THREADS) void k_hist(const int* __restrict__ dst,
                                                  int* __restrict__ cnt, int E) {
    int e = blockIdx.x * THREADS + threadIdx.x;
    if (e < E) atomicAdd(&cnt[dst[e]], 1);
}

// scan1 also emits dinv[i] = rsqrt(cnt[i]+1)
__global__ __launch_bounds__(THREADS) void k_scan1(const int* __restrict__ cnt,
                                                   int* __restrict__ rowptr,
                                                   int* __restrict__ blockSums,
                                                   float* __restrict__ dinv, int n) {
    __shared__ int part[THREADS];
    int tid = threadIdx.x;
    int base = blockIdx.x * 1024 + tid * 4;
    int v0 = (base + 0 < n) ? cnt[base + 0] : 0;
    int v1 = (base + 1 < n) ? cnt[base + 1] : 0;
    int v2 = (base + 2 < n) ? cnt[base + 2] : 0;
    int v3 = (base + 3 < n) ? cnt[base + 3] : 0;
    if (base + 0 < n) dinv[base + 0] = rsqrtf((float)v0 + 1.0f);
    if (base + 1 < n) dinv[base + 1] = rsqrtf((float)v1 + 1.0f);
    if (base + 2 < n) dinv[base + 2] = rsqrtf((float)v2 + 1.0f);
    if (base + 3 < n) dinv[base + 3] = rsqrtf((float)v3 + 1.0f);
    part[tid] = v0 + v1 + v2 + v3;
    __syncthreads();
    for (int off = 1; off < THREADS; off <<= 1) {
        int t = 0;
        if (tid >= off) t = part[tid - off];
        __syncthreads();
        if (tid >= off) part[tid] += t;
        __syncthreads();
    }
    int excl = (tid == 0) ? 0 : part[tid - 1];
    if (tid == THREADS - 1) blockSums[blockIdx.x] = part[THREADS - 1];
    int run = excl;
    if (base + 0 < n) rowptr[base + 0] = run; run += v0;
    if (base + 1 < n) rowptr[base + 1] = run; run += v1;
    if (base + 2 < n) rowptr[base + 2] = run; run += v2;
    if (base + 3 < n) rowptr[base + 3] = run;
}

__global__ __launch_bounds__(THREADS) void k_scan2(int* __restrict__ blockSums,
                                                   int* __restrict__ rowptr,
                                                   int nchunks, int n, int E) {
    __shared__ int part[THREADS];
    int tid = threadIdx.x;
    int v = (tid < nchunks) ? blockSums[tid] : 0;
    part[tid] = v;
    __syncthreads();
    for (int off = 1; off < THREADS; off <<= 1) {
        int t = 0;
        if (tid >= off) t = part[tid - off];
        __syncthreads();
        if (tid >= off) part[tid] += t;
        __syncthreads();
    }
    int excl = (tid == 0) ? 0 : part[tid - 1];
    if (tid < nchunks) blockSums[tid] = excl;
    if (tid == 0) rowptr[n] = E;
}

__global__ __launch_bounds__(THREADS) void k_scan3(int* __restrict__ rowptr,
                                                   const int* __restrict__ blockSums, int n) {
    int i = blockIdx.x * THREADS + threadIdx.x;
    if (i < n) rowptr[i] += blockSums[i >> 10];
}

// writes: swPair {src, dinv[src]}, sdSorted {src,dst}, edgePerm
__global__ __launch_bounds__(THREADS) void k_scatter(const int* __restrict__ src,
                                                     const int* __restrict__ dst,
                                                     const int* __restrict__ rowptr,
                                                     const float* __restrict__ dinv,
                                                     int* __restrict__ cursor,
                                                     int2* __restrict__ swPair,
                                                     int2* __restrict__ sdSorted,
                                                     int* __restrict__ edgePerm, int E) {
    int e = blockIdx.x * THREADS + threadIdx.x;
    if (e >= E) return;
    int d = dst[e];
    int s = src[e];
    int pos = rowptr[d] + atomicAdd(&cursor[d], 1);
    swPair[pos] = make_int2(s, __float_as_int(dinv[s]));
    sdSorted[pos] = make_int2(s, d);
    edgePerm[pos] = e;
}

// ========= W-pack: W [128][128] f32 (x2) -> MFMA B-fragments fp16 (16x16) =========
__global__ __launch_bounds__(THREADS) void k_pack_w(const float* __restrict__ W1,
                                                    const float* __restrict__ W2,
                                                    _Float16* __restrict__ wp1,
                                                    _Float16* __restrict__ wp2) {
    int t = blockIdx.x * THREADS + threadIdx.x;   // 0..4095
    const float* W = (t < 2048) ? W1 : W2;
    _Float16* wp = (t < 2048) ? wp1 : wp2;
    int tt = t & 2047;
    int lane = tt & 63;
    int fi = tt >> 6;          // ks*8+nt
    int nt = fi & 7, ks = fi >> 3;
    int krow = ks * 32 + (lane >> 4) * 8;
    int col = nt * 16 + (lane & 15);
    f16x8 v;
#pragma unroll
    for (int i = 0; i < 8; i++) v[i] = (_Float16)W[(size_t)(krow + i) * 128 + col];
    *(f16x8*)(wp + (size_t)tt * 8) = v;
}

// ========= MFMA GEMM (f32 A): C16[M][128] = bf16( A[M][128] @ W ) =========
__global__ __launch_bounds__(THREADS) void k_gemm_mfma_f32(const float* __restrict__ A,
                                                           const _Float16* __restrict__ wpack,
                                                           __bf16* __restrict__ C16, int M) {
    __shared__ _Float16 wsh[2048 * 8];   // 32 KB
    int tid = threadIdx.x;
    {
        const int4* g = (const int4*)wpack;
        int4* l = (int4*)wsh;
#pragma unroll
        for (int i = 0; i < 8; i++) l[tid + i * 256] = g[tid + i * 256];
    }
    int w = tid >> 6, lane = tid & 63;
    int m = lane & 15, kg = lane >> 4;
    int n0 = lane & 15, rowg = lane >> 4;
    int tile0 = blockIdx.x * 16 + w * 4;
    __syncthreads();
    const f16x8* wfr = ((const f16x8*)wsh) + lane;

    for (int t = 0; t < 4; t++) {
        int row = (tile0 + t) * 16 + m;
        f16x8 a[4];
        if (row < M) {
            const float* pa = A + (size_t)row * 128 + kg * 8;
#pragma unroll
            for (int ks = 0; ks < 4; ks++) {
                float4 lo = *(const float4*)(pa + ks * 32);
                float4 hi = *(const float4*)(pa + ks * 32 + 4);
                f16x8 v;
                v[0] = (_Float16)lo.x; v[1] = (_Float16)lo.y;
                v[2] = (_Float16)lo.z; v[3] = (_Float16)lo.w;
                v[4] = (_Float16)hi.x; v[5] = (_Float16)hi.y;
                v[6] = (_Float16)hi.z; v[7] = (_Float16)hi.w;
                a[ks] = v;
            }
        } else {
#pragma unroll
            for (int ks = 0; ks < 4; ks++) { f16x8 z = {}; a[ks] = z; }
        }
        f32x4 acc[8];
#pragma unroll
        for (int i = 0; i < 8; i++) acc[i] = (f32x4){0.f, 0.f, 0.f, 0.f};
#pragma unroll
        for (int ks = 0; ks < 4; ks++) {
#pragma unroll
            for (int nt = 0; nt < 8; nt++) {
                f16x8 b = wfr[(ks * 8 + nt) * 64];
                acc[nt] = __builtin_amdgcn_mfma_f32_16x16x32_f16(a[ks], b, acc[nt], 0, 0, 0);
            }
        }
#pragma unroll
        for (int nt = 0; nt < 8; nt++) {
#pragma unroll
            for (int r = 0; r < 4; r++) {
                int ro = (tile0 + t) * 16 + rowg * 4 + r;
                if (ro < M) C16[(size_t)ro * 128 + nt * 16 + n0] = (__bf16)acc[nt][r];
            }
        }
    }
}

// ========= MFMA GEMM (fp16 A): same, A loaded directly from h16 =========
__global__ __launch_bounds__(THREADS) void k_gemm_mfma_f16(const _Float16* __restrict__ A,
                                                           const _Float16* __restrict__ wpack,
                                                           __bf16* __restrict__ C16, int M) {
    __shared__ _Float16 wsh[2048 * 8];   // 32 KB
    int tid = threadIdx.x;
    {
        const int4* g = (const int4*)wpack;
        int4* l = (int4*)wsh;
#pragma unroll
        for (int i = 0; i < 8; i++) l[tid + i * 256] = g[tid + i * 256];
    }
    int w = tid >> 6, lane = tid & 63;
    int m = lane & 15, kg = lane >> 4;
    int n0 = lane & 15, rowg = lane >> 4;
    int tile0 = blockIdx.x * 16 + w * 4;
    __syncthreads();
    const f16x8* wfr = ((const f16x8*)wsh) + lane;

    for (int t = 0; t < 4; t++) {
        int row = (tile0 + t) * 16 + m;
        f16x8 a[4];
        if (row < M) {
            const _Float16* pa = A + (size_t)row * 128 + kg * 8;
#pragma unroll
            for (int ks = 0; ks < 4; ks++) a[ks] = *(const f16x8*)(pa + ks * 32);
        } else {
#pragma unroll
            for (int ks = 0; ks < 4; ks++) { f16x8 z = {}; a[ks] = z; }
        }
        f32x4 acc[8];
#pragma unroll
        for (int i = 0; i < 8; i++) acc[i] = (f32x4){0.f, 0.f, 0.f, 0.f};
#pragma unroll
        for (int ks = 0; ks < 4; ks++) {
#pragma unroll
            for (int nt = 0; nt < 8; nt++) {
                f16x8 b = wfr[(ks * 8 + nt) * 64];
                acc[nt] = __builtin_amdgcn_mfma_f32_16x16x32_f16(a[ks], b, acc[nt], 0, 0, 0);
            }
        }
#pragma unroll
        for (int nt = 0; nt < 8; nt++) {
#pragma unroll
            for (int r = 0; r < 4; r++) {
                int ro = (tile0 + t) * 16 + rowg * 4 + r;
                if (ro < M) C16[(size_t)ro * 128 + nt * 16 + n0] = (__bf16)acc[nt][r];
            }
        }
    }
}

// ===== gather-aggregate (bf16 gather, self-term from xw16, fp16 h out) =====
__global__ __launch_bounds__(THREADS) void k_gather_agg(const int* __restrict__ rowptr,
                                                        const int2* __restrict__ swPair,
                                                        const __bf16* __restrict__ xw16,
                                                        const float* __restrict__ dinv,
                                                        const float* __restrict__ bias,
                                                        _Float16* __restrict__ h16, int n) {
    int node = blockIdx.x * 4 + (threadIdx.x >> 6);
    int lane = threadIdx.x & 63;
    int q = lane >> 4;
    int c = lane & 15;          // channels c*8 .. c*8+7
    if (node >= n) return;
    int beg = rowptr[node], end = rowptr[node + 1];
    float di = dinv[node];

    float acc[8];
#pragma unroll
    for (int i = 0; i < 8; i++) acc[i] = 0.f;

    int j = beg;
    for (; j + 15 < end; j += 16) {
        int2 pw0 = swPair[j + q];
        int2 pw1 = swPair[j + 4 + q];
        int2 pw2 = swPair[j + 8 + q];
        int2 pw3 = swPair[j + 12 + q];
        bf16x8 v0 = *(const bf16x8*)(xw16 + (size_t)pw0.x * 128 + c * 8);
        bf16x8 v1 = *(const bf16x8*)(xw16 + (size_t)pw1.x * 128 + c * 8);
        bf16x8 v2 = *(const bf16x8*)(xw16 + (size_t)pw2.x * 128 + c * 8);
        bf16x8 v3 = *(const bf16x8*)(xw16 + (size_t)pw3.x * 128 + c * 8);
        float w0 = __int_as_float(pw0.y);
        float w1 = __int_as_float(pw1.y);
        float w2 = __int_as_float(pw2.y);
        float w3 = __int_as_float(pw3.y);
#pragma unroll
        for (int i = 0; i < 8; i++) {
            acc[i] = fmaf((float)v0[i], w0, acc[i]);
            acc[i] = fmaf((float)v1[i], w1, acc[i]);
            acc[i] = fmaf((float)v2[i], w2, acc[i]);
            acc[i] = fmaf((float)v3[i], w3, acc[i]);
        }
    }
    for (; j + 7 < end; j += 8) {
        int2 pw0 = swPair[j + q];
        int2 pw1 = swPair[j + 4 + q];
        bf16x8 v0 = *(const bf16x8*)(xw16 + (size_t)pw0.x * 128 + c * 8);
        bf16x8 v1 = *(const bf16x8*)(xw16 + (size_t)pw1.x * 128 + c * 8);
        float w0 = __int_as_float(pw0.y);
        float w1 = __int_as_float(pw1.y);
#pragma unroll
        for (int i = 0; i < 8; i++) {
            acc[i] = fmaf((float)v0[i], w0, acc[i]);
            acc[i] = fmaf((float)v1[i], w1, acc[i]);
        }
    }
    for (; j + 3 < end; j += 4) {
        int2 pw = swPair[j + q];
        bf16x8 v = *(const bf16x8*)(xw16 + (size_t)pw.x * 128 + c * 8);
        float w = __int_as_float(pw.y);
#pragma unroll
        for (int i = 0; i < 8; i++) acc[i] = fmaf((float)v[i], w, acc[i]);
    }
    int rem = end - j;
    if (q < rem) {
        int2 pw = swPair[j + q];
        bf16x8 v = *(const bf16x8*)(xw16 + (size_t)pw.x * 128 + c * 8);
        float w = __int_as_float(pw.y);
#pragma unroll
        for (int i = 0; i < 8; i++) acc[i] = fmaf((float)v[i], w, acc[i]);
    }

    // merge quarters
#pragma unroll
    for (int i = 0; i < 8; i++) {
        acc[i] += __shfl_xor(acc[i], 16);
        acc[i] += __shfl_xor(acc[i], 32);
    }

    if (q == 0) {
        bf16x8 sv = *(const bf16x8*)(xw16 + (size_t)node * 128 + c * 8);
        float4 b0 = *(const float4*)(bias + c * 8);
        float4 b1 = *(const float4*)(bias + c * 8 + 4);
        float bb[8] = {b0.x, b0.y, b0.z, b0.w, b1.x, b1.y, b1.z, b1.w};
        float dd = di * di;
        f16x8 r16;
#pragma unroll
        for (int i = 0; i < 8; i++) {
            float r = fmaf(acc[i], di, fmaf((float)sv[i], dd, bb[i]));
            r16[i] = (_Float16)fmaxf(r, 0.f);
        }
        *(f16x8*)(h16 + (size_t)node * 128 + c * 8) = r16;
    }
}

// ====== B-pack for 32x32x16 MFMA: fc1w [256][128] -> fragments fp16 ======
// frag fi = s*4+nt (s<16 ksteps, nt<4 ntiles); lane elem i:
//   bp[fi*64*8 + lane*8 + i] = fc1w[s*16 + (lane>>5)*8 + i][nt*32 + (lane&31)]
__global__ __launch_bounds__(THREADS) void k_pack_b32(const float* __restrict__ fc1w,
                                                      _Float16* __restrict__ bp) {
    int t = blockIdx.x * THREADS + threadIdx.x;   // 0..4095
    int lane = t & 63;
    int fi = t >> 6;          // s*4+nt
    int nt = fi & 3, s = fi >> 2;
    int krow = s * 16 + (lane >> 5) * 8;
    int col = nt * 32 + (lane & 31);
    f16x8 v;
#pragma unroll
    for (int i = 0; i < 8; i++) v[i] = (_Float16)fc1w[(size_t)(krow + i) * 128 + col];
    *(f16x8*)(bp + (size_t)t * 8) = v;
}

// ====== edge head (MFMA fp16 32x32x16, LDS B, 2x 32-edge tiles/wave) ======
// Wave computes 32 edges/tile: each B ds_read feeds 2x the output of the 16x16
// shape (B-LDS traffic per edge halves) with ONE shared acc[4] (64 VGPR) —
// no r15-style register duplication. Steps s and s+8 (prod/diff halves of ef)
// share x/y chunks, so gather count stays 32 loads/edge. The 8-iteration
// k-loop software-pipelines loads under MFMAs naturally.
__global__ __launch_bounds__(THREADS) void k_edge_head_mfma32(
        const int2* __restrict__ sdSorted,
        const int* __restrict__ edgePerm,
        const _Float16* __restrict__ h16,
        const _Float16* __restrict__ bpack32,
        const float* __restrict__ fc1b,
        const float* __restrict__ fc2w,
        const float* __restrict__ fc2b,
        float* __restrict__ out, int E) {
    __shared__ _Float16 bsh[4096 * 8];   // 64 KB

    int tid = threadIdx.x;
    {
        const int4* gsrc = (const int4*)bpack32;
        int4* ldst = (int4*)bsh;
#pragma unroll
        for (int i = 0; i < 16; i++) ldst[tid + i * 256] = gsrc[tid + i * 256];
    }

    int w = tid >> 6;
    int lane = tid & 63;
    int er = lane & 31;       // edge row within 32-edge tile
    int kh = (lane >> 5) * 8; // k-half offset within each 16-wide k-step
    int col = lane & 31;      // output column group
    int half = lane >> 5;
    const f16x8* bfr = ((const f16x8*)bsh) + lane;
    float b2 = fc2b[0];

    float bb[4], ww[4];
#pragma unroll
    for (int nt = 0; nt < 4; nt++) {
        bb[nt] = fc1b[nt * 32 + col];
        ww[nt] = fc2w[nt * 32 + col];
    }

    __syncthreads();

    for (int tt = 0; tt < 2; tt++) {
        int tile = blockIdx.x * 8 + w * 2 + tt;   // 8 tiles (256 edges)/block
        int p = tile * 32 + er;
        int2 sd = (p < E) ? sdSorted[p] : make_int2(0, 0);
        const _Float16* px = h16 + (size_t)sd.x * 128 + kh;
        const _Float16* py = h16 + (size_t)sd.y * 128 + kh;

        f32x16 acc[4];
#pragma unroll
        for (int nt = 0; nt < 4; nt++) {
#pragma unroll
            for (int r = 0; r < 16; r++) acc[nt][r] = bb[nt];
        }

#pragma unroll
        for (int s = 0; s < 8; s++) {
            f16x8 xv = *(const f16x8*)(px + s * 16);
            f16x8 yv = *(const f16x8*)(py + s * 16);
            f16x8 pa = xv * yv;    // prod half: ef[k], k = s*16+kh (steps 0..7)
            f16x8 pd = xv - yv;    // diff half: ef[128+k]        (steps 8..15)
#pragma unroll
            for (int nt = 0; nt < 4; nt++) {
                f16x8 bA = bfr[(s * 4 + nt) * 64];
                acc[nt] = __builtin_amdgcn_mfma_f32_32x32x16_f16(pa, bA, acc[nt], 0, 0, 0);
            }
#pragma unroll
            for (int nt = 0; nt < 4; nt++) {
                f16x8 bB = bfr[((s + 8) * 4 + nt) * 64];
                acc[nt] = __builtin_amdgcn_mfma_f32_32x32x16_f16(pd, bB, acc[nt], 0, 0, 0);
            }
        }

        // epilogue: C/D 32x32 mapping: col = lane&31, row = (r&3)+8*(r>>2)+4*half
        float partial[16];
#pragma unroll
        for (int r = 0; r < 16; r++) {
            float sum = fmaxf(acc[0][r], 0.f) * ww[0];
            sum = fmaf(fmaxf(acc[1][r], 0.f), ww[1], sum);
            sum = fmaf(fmaxf(acc[2][r], 0.f), ww[2], sum);
            sum = fmaf(fmaxf(acc[3][r], 0.f), ww[3], sum);
            partial[r] = sum;
        }
#pragma unroll
        for (int r = 0; r < 16; r++) {
            partial[r] += __shfl_xor(partial[r], 1);
            partial[r] += __shfl_xor(partial[r], 2);
            partial[r] += __shfl_xor(partial[r], 4);
            partial[r] += __shfl_xor(partial[r], 8);
            partial[r] += __shfl_xor(partial[r], 16);
        }
        if (col == 0) {
#pragma unroll
            for (int r = 0; r < 16; r++) {
                int row = (r & 3) + 8 * (r >> 2) + 4 * half;
                int qq = tile * 32 + row;
                if (qq < E) out[edgePerm[qq]] = 1.0f / (1.0f + expf(-(partial[r] + b2)));
            }
        }
    }
}

// ================= host =================
extern "C" void kernel_launch(void* const* d_in, const int* in_sizes, int n_in,
                              void* d_out, int out_size, void* d_ws, size_t ws_size,
                              hipStream_t stream) {
    const float* x    = (const float*)d_in[0];
    const int*   ei   = (const int*)d_in[1];
    const float* W1   = (const float*)d_in[2];
    const float* b1   = (const float*)d_in[3];
    const float* W2   = (const float*)d_in[4];
    const float* b2   = (const float*)d_in[5];
    const float* fc1w = (const float*)d_in[6];
    const float* fc1b = (const float*)d_in[7];
    const float* fc2w = (const float*)d_in[8];
    const float* fc2b = (const float*)d_in[9];

    int N = in_sizes[0] / 128;
    int E = in_sizes[1] / 2;
    const int* src = ei;
    const int* dst = ei + E;

    // ---- workspace layout ----
    char* ws = (char*)d_ws;
    size_t off = 0;
    auto alloc = [&](size_t bytes) { char* p = ws + off; off += (bytes + 255) & ~(size_t)255; return p; };
    int*      cnt       = (int*)     alloc((size_t)N * 4);
    int*      rowptr    = (int*)     alloc(((size_t)N + 1) * 4);
    int*      cursor    = (int*)     alloc((size_t)N * 4);
    int*      blockSums = (int*)     alloc(256 * 4);
    int2*     swPair    = (int2*)    alloc((size_t)E * 8);
    int2*     sdSorted  = (int2*)    alloc((size_t)E * 8);
    int*      edgePerm  = (int*)     alloc((size_t)E * 4);
    float*    dinv      = (float*)   alloc((size_t)N * 4);
    _Float16* bpack32   = (_Float16*)alloc((size_t)4096 * 8 * 2);   // 64 KB
    _Float16* wp1       = (_Float16*)alloc((size_t)2048 * 8 * 2);   // 32 KB
    _Float16* wp2       = (_Float16*)alloc((size_t)2048 * 8 * 2);   // 32 KB
    __bf16*   xw16      = (__bf16*)  alloc((size_t)N * 128 * 2);
    _Float16* h16       = (_Float16*)alloc((size_t)N * 128 * 2);

    int gN     = (N + THREADS - 1) / THREADS;
    int gE     = (E + THREADS - 1) / THREADS;
    int nchunk = (N + 1023) / 1024;
    int nTileG = (N + 15) / 16;
    int gGemm  = (nTileG + 15) / 16;
    int gGath  = (N + 3) / 4;
    int gHead  = (E + 255) / 256;

    // ---- CSR build + degrees + packs ----
    hipMemsetAsync(cnt, 0, (size_t)N * 4, stream);
    k_hist<<<gE, THREADS, 0, stream>>>(dst, cnt, E);
    k_scan1<<<nchunk, THREADS, 0, stream>>>(cnt, rowptr, blockSums, dinv, N);
    k_scan2<<<1, THREADS, 0, stream>>>(blockSums, rowptr, nchunk, N, E);
    k_scan3<<<gN, THREADS, 0, stream>>>(rowptr, blockSums, N);
    hipMemsetAsync(cursor, 0, (size_t)N * 4, stream);
    k_scatter<<<gE, THREADS, 0, stream>>>(src, dst, rowptr, dinv, cursor,
                                          swPair, sdSorted, edgePerm, E);
    k_pack_b32<<<16, THREADS, 0, stream>>>(fc1w, bpack32);
    k_pack_w<<<16, THREADS, 0, stream>>>(W1, W2, wp1, wp2);

    // ---- layer 1 (MFMA GEMM) ----
    k_gemm_mfma_f32<<<gGemm, THREADS, 0, stream>>>(x, wp1, xw16, N);
    k_gather_agg<<<gGath, THREADS, 0, stream>>>(rowptr, swPair, xw16, dinv, b1, h16, N);

    // ---- layer 2 (MFMA GEMM) ----
    k_gemm_mfma_f16<<<gGemm, THREADS, 0, stream>>>(h16, wp2, xw16, N);
    k_gather_agg<<<gGath, THREADS, 0, stream>>>(rowptr, swPair, xw16, dinv, b2, h16, N);

    // ---- edge head (MFMA fp16 32x32, LDS B) ----
    k_edge_head_mfma32<<<gHead, THREADS, 0, stream>>>(sdSorted, edgePerm,
                                                      h16, bpack32, fc1b, fc2w, fc2b,
                                                      (float*)d_out, E);
}

// Round 20
// 491.970 us; speedup vs baseline: 1.6573x; 1.6573x over previous
//
#include <hip/hip_runtime.h>

#define THREADS 256

typedef __bf16    bf16x8 __attribute__((ext_vector_type(8)));
typedef _Float16  f16x8  __attribute__((ext_vector_type(8)));
typedef float     f32x4  __attribute__((ext_vector_type(4)));

// ================= CSR build: histogram -> scan -> scatter =================

__global__ __launch_bounds__(THREADS) void k_hist(const int* __restrict__ dst,
                                                  int* __restrict__ cnt, int E) {
    int e = blockIdx.x * THREADS + threadIdx.x;
    if (e < E) atomicAdd(&cnt[dst[e]], 1);
}

// scan1 also emits dinv[i] = rsqrt(cnt[i]+1)
__global__ __launch_bounds__(THREADS) void k_scan1(const int* __restrict__ cnt,
                                                   int* __restrict__ rowptr,
                                                   int* __restrict__ blockSums,
                                                   float* __restrict__ dinv, int n) {
    __shared__ int part[THREADS];
    int tid = threadIdx.x;
    int base = blockIdx.x * 1024 + tid * 4;
    int v0 = (base + 0 < n) ? cnt[base + 0] : 0;
    int v1 = (base + 1 < n) ? cnt[base + 1] : 0;
    int v2 = (base + 2 < n) ? cnt[base + 2] : 0;
    int v3 = (base + 3 < n) ? cnt[base + 3] : 0;
    if (base + 0 < n) dinv[base + 0] = rsqrtf((float)v0 + 1.0f);
    if (base + 1 < n) dinv[base + 1] = rsqrtf((float)v1 + 1.0f);
    if (base + 2 < n) dinv[base + 2] = rsqrtf((float)v2 + 1.0f);
    if (base + 3 < n) dinv[base + 3] = rsqrtf((float)v3 + 1.0f);
    part[tid] = v0 + v1 + v2 + v3;
    __syncthreads();
    for (int off = 1; off < THREADS; off <<= 1) {
        int t = 0;
        if (tid >= off) t = part[tid - off];
        __syncthreads();
        if (tid >= off) part[tid] += t;
        __syncthreads();
    }
    int excl = (tid == 0) ? 0 : part[tid - 1];
    if (tid == THREADS - 1) blockSums[blockIdx.x] = part[THREADS - 1];
    int run = excl;
    if (base + 0 < n) rowptr[base + 0] = run; run += v0;
    if (base + 1 < n) rowptr[base + 1] = run; run += v1;
    if (base + 2 < n) rowptr[base + 2] = run; run += v2;
    if (base + 3 < n) rowptr[base + 3] = run;
}

__global__ __launch_bounds__(THREADS) void k_scan2(int* __restrict__ blockSums,
                                                   int* __restrict__ rowptr,
                                                   int nchunks, int n, int E) {
    __shared__ int part[THREADS];
    int tid = threadIdx.x;
    int v = (tid < nchunks) ? blockSums[tid] : 0;
    part[tid] = v;
    __syncthreads();
    for (int off = 1; off < THREADS; off <<= 1) {
        int t = 0;
        if (tid >= off) t = part[tid - off];
        __syncthreads();
        if (tid >= off) part[tid] += t;
        __syncthreads();
    }
    int excl = (tid == 0) ? 0 : part[tid - 1];
    if (tid < nchunks) blockSums[tid] = excl;
    if (tid == 0) rowptr[n] = E;
}

__global__ __launch_bounds__(THREADS) void k_scan3(int* __restrict__ rowptr,
                                                   const int* __restrict__ blockSums, int n) {
    int i = blockIdx.x * THREADS + threadIdx.x;
    if (i < n) rowptr[i] += blockSums[i >> 10];
}

// writes: swPair {src, dinv[src]}, sdSorted {src,dst}, edgePerm
__global__ __launch_bounds__(THREADS) void k_scatter(const int* __restrict__ src,
                                                     const int* __restrict__ dst,
                                                     const int* __restrict__ rowptr,
                                                     const float* __restrict__ dinv,
                                                     int* __restrict__ cursor,
                                                     int2* __restrict__ swPair,
                                                     int2* __restrict__ sdSorted,
                                                     int* __restrict__ edgePerm, int E) {
    int e = blockIdx.x * THREADS + threadIdx.x;
    if (e >= E) return;
    int d = dst[e];
    int s = src[e];
    int pos = rowptr[d] + atomicAdd(&cursor[d], 1);
    swPair[pos] = make_int2(s, __float_as_int(dinv[s]));
    sdSorted[pos] = make_int2(s, d);
    edgePerm[pos] = e;
}

// ========= W-pack: W [128][128] f32 (x2) -> MFMA B-fragments fp16 =========
__global__ __launch_bounds__(THREADS) void k_pack_w(const float* __restrict__ W1,
                                                    const float* __restrict__ W2,
                                                    _Float16* __restrict__ wp1,
                                                    _Float16* __restrict__ wp2) {
    int t = blockIdx.x * THREADS + threadIdx.x;   // 0..4095
    const float* W = (t < 2048) ? W1 : W2;
    _Float16* wp = (t < 2048) ? wp1 : wp2;
    int tt = t & 2047;
    int lane = tt & 63;
    int fi = tt >> 6;          // ks*8+nt
    int nt = fi & 7, ks = fi >> 3;
    int krow = ks * 32 + (lane >> 4) * 8;
    int col = nt * 16 + (lane & 15);
    f16x8 v;
#pragma unroll
    for (int i = 0; i < 8; i++) v[i] = (_Float16)W[(size_t)(krow + i) * 128 + col];
    *(f16x8*)(wp + (size_t)tt * 8) = v;
}

// ========= MFMA GEMM (f32 A): C16[M][128] = bf16( A[M][128] @ W ) =========
__global__ __launch_bounds__(THREADS) void k_gemm_mfma_f32(const float* __restrict__ A,
                                                           const _Float16* __restrict__ wpack,
                                                           __bf16* __restrict__ C16, int M) {
    __shared__ _Float16 wsh[2048 * 8];   // 32 KB
    int tid = threadIdx.x;
    {
        const int4* g = (const int4*)wpack;
        int4* l = (int4*)wsh;
#pragma unroll
        for (int i = 0; i < 8; i++) l[tid + i * 256] = g[tid + i * 256];
    }
    int w = tid >> 6, lane = tid & 63;
    int m = lane & 15, kg = lane >> 4;
    int n0 = lane & 15, rowg = lane >> 4;
    int tile0 = blockIdx.x * 16 + w * 4;
    __syncthreads();
    const f16x8* wfr = ((const f16x8*)wsh) + lane;

    for (int t = 0; t < 4; t++) {
        int row = (tile0 + t) * 16 + m;
        f16x8 a[4];
        if (row < M) {
            const float* pa = A + (size_t)row * 128 + kg * 8;
#pragma unroll
            for (int ks = 0; ks < 4; ks++) {
                float4 lo = *(const float4*)(pa + ks * 32);
                float4 hi = *(const float4*)(pa + ks * 32 + 4);
                f16x8 v;
                v[0] = (_Float16)lo.x; v[1] = (_Float16)lo.y;
                v[2] = (_Float16)lo.z; v[3] = (_Float16)lo.w;
                v[4] = (_Float16)hi.x; v[5] = (_Float16)hi.y;
                v[6] = (_Float16)hi.z; v[7] = (_Float16)hi.w;
                a[ks] = v;
            }
        } else {
#pragma unroll
            for (int ks = 0; ks < 4; ks++) { f16x8 z = {}; a[ks] = z; }
        }
        f32x4 acc[8];
#pragma unroll
        for (int i = 0; i < 8; i++) acc[i] = (f32x4){0.f, 0.f, 0.f, 0.f};
#pragma unroll
        for (int ks = 0; ks < 4; ks++) {
#pragma unroll
            for (int nt = 0; nt < 8; nt++) {
                f16x8 b = wfr[(ks * 8 + nt) * 64];
                acc[nt] = __builtin_amdgcn_mfma_f32_16x16x32_f16(a[ks], b, acc[nt], 0, 0, 0);
            }
        }
#pragma unroll
        for (int nt = 0; nt < 8; nt++) {
#pragma unroll
            for (int r = 0; r < 4; r++) {
                int ro = (tile0 + t) * 16 + rowg * 4 + r;
                if (ro < M) C16[(size_t)ro * 128 + nt * 16 + n0] = (__bf16)acc[nt][r];
            }
        }
    }
}

// ========= MFMA GEMM (fp16 A): same, A loaded directly from h16 =========
__global__ __launch_bounds__(THREADS) void k_gemm_mfma_f16(const _Float16* __restrict__ A,
                                                           const _Float16* __restrict__ wpack,
                                                           __bf16* __restrict__ C16, int M) {
    __shared__ _Float16 wsh[2048 * 8];   // 32 KB
    int tid = threadIdx.x;
    {
        const int4* g = (const int4*)wpack;
        int4* l = (int4*)wsh;
#pragma unroll
        for (int i = 0; i < 8; i++) l[tid + i * 256] = g[tid + i * 256];
    }
    int w = tid >> 6, lane = tid & 63;
    int m = lane & 15, kg = lane >> 4;
    int n0 = lane & 15, rowg = lane >> 4;
    int tile0 = blockIdx.x * 16 + w * 4;
    __syncthreads();
    const f16x8* wfr = ((const f16x8*)wsh) + lane;

    for (int t = 0; t < 4; t++) {
        int row = (tile0 + t) * 16 + m;
        f16x8 a[4];
        if (row < M) {
            const _Float16* pa = A + (size_t)row * 128 + kg * 8;
#pragma unroll
            for (int ks = 0; ks < 4; ks++) a[ks] = *(const f16x8*)(pa + ks * 32);
        } else {
#pragma unroll
            for (int ks = 0; ks < 4; ks++) { f16x8 z = {}; a[ks] = z; }
        }
        f32x4 acc[8];
#pragma unroll
        for (int i = 0; i < 8; i++) acc[i] = (f32x4){0.f, 0.f, 0.f, 0.f};
#pragma unroll
        for (int ks = 0; ks < 4; ks++) {
#pragma unroll
            for (int nt = 0; nt < 8; nt++) {
                f16x8 b = wfr[(ks * 8 + nt) * 64];
                acc[nt] = __builtin_amdgcn_mfma_f32_16x16x32_f16(a[ks], b, acc[nt], 0, 0, 0);
            }
        }
#pragma unroll
        for (int nt = 0; nt < 8; nt++) {
#pragma unroll
            for (int r = 0; r < 4; r++) {
                int ro = (tile0 + t) * 16 + rowg * 4 + r;
                if (ro < M) C16[(size_t)ro * 128 + nt * 16 + n0] = (__bf16)acc[nt][r];
            }
        }
    }
}

// ===== gather-aggregate (bf16 gather, self-term from xw16, fp16 h out) =====
__global__ __launch_bounds__(THREADS) void k_gather_agg(const int* __restrict__ rowptr,
                                                        const int2* __restrict__ swPair,
                                                        const __bf16* __restrict__ xw16,
                                                        const float* __restrict__ dinv,
                                                        const float* __restrict__ bias,
                                                        _Float16* __restrict__ h16, int n) {
    int node = blockIdx.x * 4 + (threadIdx.x >> 6);
    int lane = threadIdx.x & 63;
    int q = lane >> 4;
    int c = lane & 15;          // channels c*8 .. c*8+7
    if (node >= n) return;
    int beg = rowptr[node], end = rowptr[node + 1];
    float di = dinv[node];

    float acc[8];
#pragma unroll
    for (int i = 0; i < 8; i++) acc[i] = 0.f;

    int j = beg;
    for (; j + 15 < end; j += 16) {
        int2 pw0 = swPair[j + q];
        int2 pw1 = swPair[j + 4 + q];
        int2 pw2 = swPair[j + 8 + q];
        int2 pw3 = swPair[j + 12 + q];
        bf16x8 v0 = *(const bf16x8*)(xw16 + (size_t)pw0.x * 128 + c * 8);
        bf16x8 v1 = *(const bf16x8*)(xw16 + (size_t)pw1.x * 128 + c * 8);
        bf16x8 v2 = *(const bf16x8*)(xw16 + (size_t)pw2.x * 128 + c * 8);
        bf16x8 v3 = *(const bf16x8*)(xw16 + (size_t)pw3.x * 128 + c * 8);
        float w0 = __int_as_float(pw0.y);
        float w1 = __int_as_float(pw1.y);
        float w2 = __int_as_float(pw2.y);
        float w3 = __int_as_float(pw3.y);
#pragma unroll
        for (int i = 0; i < 8; i++) {
            acc[i] = fmaf((float)v0[i], w0, acc[i]);
            acc[i] = fmaf((float)v1[i], w1, acc[i]);
            acc[i] = fmaf((float)v2[i], w2, acc[i]);
            acc[i] = fmaf((float)v3[i], w3, acc[i]);
        }
    }
    for (; j + 7 < end; j += 8) {
        int2 pw0 = swPair[j + q];
        int2 pw1 = swPair[j + 4 + q];
        bf16x8 v0 = *(const bf16x8*)(xw16 + (size_t)pw0.x * 128 + c * 8);
        bf16x8 v1 = *(const bf16x8*)(xw16 + (size_t)pw1.x * 128 + c * 8);
        float w0 = __int_as_float(pw0.y);
        float w1 = __int_as_float(pw1.y);
#pragma unroll
        for (int i = 0; i < 8; i++) {
            acc[i] = fmaf((float)v0[i], w0, acc[i]);
            acc[i] = fmaf((float)v1[i], w1, acc[i]);
        }
    }
    for (; j + 3 < end; j += 4) {
        int2 pw = swPair[j + q];
        bf16x8 v = *(const bf16x8*)(xw16 + (size_t)pw.x * 128 + c * 8);
        float w = __int_as_float(pw.y);
#pragma unroll
        for (int i = 0; i < 8; i++) acc[i] = fmaf((float)v[i], w, acc[i]);
    }
    int rem = end - j;
    if (q < rem) {
        int2 pw = swPair[j + q];
        bf16x8 v = *(const bf16x8*)(xw16 + (size_t)pw.x * 128 + c * 8);
        float w = __int_as_float(pw.y);
#pragma unroll
        for (int i = 0; i < 8; i++) acc[i] = fmaf((float)v[i], w, acc[i]);
    }

    // merge quarters
#pragma unroll
    for (int i = 0; i < 8; i++) {
        acc[i] += __shfl_xor(acc[i], 16);
        acc[i] += __shfl_xor(acc[i], 32);
    }

    if (q == 0) {
        bf16x8 sv = *(const bf16x8*)(xw16 + (size_t)node * 128 + c * 8);
        float4 b0 = *(const float4*)(bias + c * 8);
        float4 b1 = *(const float4*)(bias + c * 8 + 4);
        float bb[8] = {b0.x, b0.y, b0.z, b0.w, b1.x, b1.y, b1.z, b1.w};
        float dd = di * di;
        f16x8 r16;
#pragma unroll
        for (int i = 0; i < 8; i++) {
            float r = fmaf(acc[i], di, fmaf((float)sv[i], dd, bb[i]));
            r16[i] = (_Float16)fmaxf(r, 0.f);
        }
        *(f16x8*)(h16 + (size_t)node * 128 + c * 8) = r16;
    }
}

// ================= B-pack: fc1w [256][128] f32 -> MFMA B-fragments fp16 =================
__global__ __launch_bounds__(THREADS) void k_pack_b(const float* __restrict__ fc1w,
                                                    _Float16* __restrict__ bpack) {
    int t = blockIdx.x * THREADS + threadIdx.x;   // 0..4095
    int lane = t & 63;
    int fi = t >> 6;          // ks*8+nt
    int nt = fi & 7, ks = fi >> 3;
    int krow = ks * 32 + (lane >> 4) * 8;
    int col = nt * 16 + (lane & 15);
    f16x8 v;
#pragma unroll
    for (int i = 0; i < 8; i++) v[i] = (_Float16)fc1w[(size_t)(krow + i) * 128 + col];
    *(f16x8*)(bpack + (size_t)t * 8) = v;
}

// ================= edge head (MFMA fp16, LDS B, 4 tiles/wave, dbuf pipeline) ====
// r13/r14 proven configuration: 256 thr, 4 waves, 64KB LDS B, 100 VGPR, no spill.
__global__ __launch_bounds__(THREADS) void k_edge_head_mfma(const int2* __restrict__ sdSorted,
                                                            const int* __restrict__ edgePerm,
                                                            const _Float16* __restrict__ h16,
                                                            const _Float16* __restrict__ bpack,
                                                            const float* __restrict__ fc1b,
                                                            const float* __restrict__ fc2w,
                                                            const float* __restrict__ fc2b,
                                                            float* __restrict__ out, int E) {
    __shared__ _Float16 bsh[4096 * 8];   // 64 KB

    int tid = threadIdx.x;
    {
        const int4* gsrc = (const int4*)bpack;
        int4* ldst = (int4*)bsh;
#pragma unroll
        for (int i = 0; i < 16; i++) ldst[tid + i * 256] = gsrc[tid + i * 256];
    }

    int w = tid >> 6;
    int lane = tid & 63;
    int m = lane & 15;
    int kg = lane >> 4;
    int n0 = lane & 15;
    int rowg = lane >> 4;
    int tile0 = blockIdx.x * 16 + w * 4;
    const f16x8* bfr = ((const f16x8*)bsh) + lane;
    float b2 = fc2b[0];

    float bb[8], ww[8];
#pragma unroll
    for (int nt = 0; nt < 8; nt++) {
        bb[nt] = fc1b[nt * 16 + n0];
        ww[nt] = fc2w[nt * 16 + n0];
    }

    auto LOAD = [&](int t, f16x8* xl, f16x8* yl) {
        int p = (tile0 + t) * 16 + m;
        int2 sd = (p < E) ? sdSorted[p] : make_int2(0, 0);
        const _Float16* px = h16 + (size_t)sd.x * 128 + kg * 8;
        const _Float16* py = h16 + (size_t)sd.y * 128 + kg * 8;
#pragma unroll
        for (int ks = 0; ks < 4; ks++) {
            xl[ks] = *(const f16x8*)(px + ks * 32);
            yl[ks] = *(const f16x8*)(py + ks * 32);
        }
    };

    auto COMPUTE = [&](int t, const f16x8* xl, const f16x8* yl) {
        f16x8 afrag[8];
#pragma unroll
        for (int ks = 0; ks < 4; ks++) {
            afrag[ks]     = xl[ks] * yl[ks];
            afrag[ks + 4] = xl[ks] - yl[ks];
        }
        f32x4 acc[8];
#pragma unroll
        for (int nt = 0; nt < 8; nt++) acc[nt] = (f32x4){bb[nt], bb[nt], bb[nt], bb[nt]};
#pragma unroll
        for (int ks = 0; ks < 8; ks++) {
#pragma unroll
            for (int nt = 0; nt < 8; nt++) {
                f16x8 b = bfr[(ks * 8 + nt) * 64];
                acc[nt] = __builtin_amdgcn_mfma_f32_16x16x32_f16(afrag[ks], b, acc[nt], 0, 0, 0);
            }
        }
        float partial[4] = {0.f, 0.f, 0.f, 0.f};
#pragma unroll
        for (int nt = 0; nt < 8; nt++) {
#pragma unroll
            for (int r = 0; r < 4; r++) {
                float z = fmaxf(acc[nt][r], 0.f);
                partial[r] = fmaf(z, ww[nt], partial[r]);
            }
        }
#pragma unroll
        for (int r = 0; r < 4; r++) {
            partial[r] += __shfl_xor(partial[r], 1);
            partial[r] += __shfl_xor(partial[r], 2);
            partial[r] += __shfl_xor(partial[r], 4);
            partial[r] += __shfl_xor(partial[r], 8);
        }
        if (n0 == 0) {
#pragma unroll
            for (int r = 0; r < 4; r++) {
                int qq = (tile0 + t) * 16 + rowg * 4 + r;
                if (qq < E) out[edgePerm[qq]] = 1.0f / (1.0f + expf(-(partial[r] + b2)));
            }
        }
    };

    f16x8 xa[4], ya[4], xb[4], yb[4];
    LOAD(0, xa, ya);
    __syncthreads();
    LOAD(1, xb, yb);
    COMPUTE(0, xa, ya);
    LOAD(2, xa, ya);
    COMPUTE(1, xb, yb);
    LOAD(3, xb, yb);
    COMPUTE(2, xa, ya);
    COMPUTE(3, xb, yb);
}

// ================= host =================
extern "C" void kernel_launch(void* const* d_in, const int* in_sizes, int n_in,
                              void* d_out, int out_size, void* d_ws, size_t ws_size,
                              hipStream_t stream) {
    const float* x    = (const float*)d_in[0];
    const int*   ei   = (const int*)d_in[1];
    const float* W1   = (const float*)d_in[2];
    const float* b1   = (const float*)d_in[3];
    const float* W2   = (const float*)d_in[4];
    const float* b2   = (const float*)d_in[5];
    const float* fc1w = (const float*)d_in[6];
    const float* fc1b = (const float*)d_in[7];
    const float* fc2w = (const float*)d_in[8];
    const float* fc2b = (const float*)d_in[9];

    int N = in_sizes[0] / 128;
    int E = in_sizes[1] / 2;
    const int* src = ei;
    const int* dst = ei + E;

    // ---- workspace layout ----
    char* ws = (char*)d_ws;
    size_t off = 0;
    auto alloc = [&](size_t bytes) { char* p = ws + off; off += (bytes + 255) & ~(size_t)255; return p; };
    int*      cnt       = (int*)     alloc((size_t)N * 4);
    int*      rowptr    = (int*)     alloc(((size_t)N + 1) * 4);
    int*      cursor    = (int*)     alloc((size_t)N * 4);
    int*      blockSums = (int*)     alloc(256 * 4);
    int2*     swPair    = (int2*)    alloc((size_t)E * 8);
    int2*     sdSorted  = (int2*)    alloc((size_t)E * 8);
    int*      edgePerm  = (int*)     alloc((size_t)E * 4);
    float*    dinv      = (float*)   alloc((size_t)N * 4);
    _Float16* bpack     = (_Float16*)alloc((size_t)4096 * 8 * 2);   // 64 KB
    _Float16* wp1       = (_Float16*)alloc((size_t)2048 * 8 * 2);   // 32 KB
    _Float16* wp2       = (_Float16*)alloc((size_t)2048 * 8 * 2);   // 32 KB
    __bf16*   xw16      = (__bf16*)  alloc((size_t)N * 128 * 2);
    _Float16* h16       = (_Float16*)alloc((size_t)N * 128 * 2);

    int gN     = (N + THREADS - 1) / THREADS;
    int gE     = (E + THREADS - 1) / THREADS;
    int nchunk = (N + 1023) / 1024;
    int nTileG = (N + 15) / 16;
    int gGemm  = (nTileG + 15) / 16;
    int gGath  = (N + 3) / 4;
    int gHead  = (E + 255) / 256;

    // ---- CSR build + degrees + packs ----
    hipMemsetAsync(cnt, 0, (size_t)N * 4, stream);
    k_hist<<<gE, THREADS, 0, stream>>>(dst, cnt, E);
    k_scan1<<<nchunk, THREADS, 0, stream>>>(cnt, rowptr, blockSums, dinv, N);
    k_scan2<<<1, THREADS, 0, stream>>>(blockSums, rowptr, nchunk, N, E);
    k_scan3<<<gN, THREADS, 0, stream>>>(rowptr, blockSums, N);
    hipMemsetAsync(cursor, 0, (size_t)N * 4, stream);
    k_scatter<<<gE, THREADS, 0, stream>>>(src, dst, rowptr, dinv, cursor,
                                          swPair, sdSorted, edgePerm, E);
    k_pack_b<<<16, THREADS, 0, stream>>>(fc1w, bpack);
    k_pack_w<<<16, THREADS, 0, stream>>>(W1, W2, wp1, wp2);

    // ---- layer 1 (MFMA GEMM) ----
    k_gemm_mfma_f32<<<gGemm, THREADS, 0, stream>>>(x, wp1, xw16, N);
    k_gather_agg<<<gGath, THREADS, 0, stream>>>(rowptr, swPair, xw16, dinv, b1, h16, N);

    // ---- layer 2 (MFMA GEMM) ----
    k_gemm_mfma_f16<<<gGemm, THREADS, 0, stream>>>(h16, wp2, xw16, N);
    k_gather_agg<<<gGath, THREADS, 0, stream>>>(rowptr, swPair, xw16, dinv, b2, h16, N);

    // ---- edge head (MFMA fp16, LDS B, pipelined — r13/r14 proven config) ----
    k_edge_head_mfma<<<gHead, THREADS, 0, stream>>>(sdSorted, edgePerm,
                                                    h16, bpack, fc1b, fc2w, fc2b,
                                                    (float*)d_out, E);
}